// Round 8
// baseline (1078.544 us; speedup 1.0000x reference)
//
#include <hip/hip_runtime.h>

#define B 32
#define S 2048
#define I 256
#define H 256

#define NWORK  224    // GEMM worker blocks (dispatched FIRST: bid 0..223)
#define NRNN   32     // RNN blocks (bid 224..255), one per batch
#define NTILE  1024   // 512 M-tiles x 2 N-tiles
#define NFLAG  512    // 32 batches x 16 s-chunks

typedef _Float16 h2 __attribute__((ext_vector_type(2)));

__device__ __forceinline__ float fdot2(h2 a, h2 b, float c) {
#if __has_builtin(__builtin_amdgcn_fdot2)
    return __builtin_amdgcn_fdot2(a, b, c, false);
#else
    return fmaf((float)a[1], (float)b[1], fmaf((float)a[0], (float)b[0], c));
#endif
}

// lgkm-only workgroup barrier. imm 0xC07F = vmcnt(63) expcnt(7) lgkmcnt(0).
__device__ __forceinline__ void lds_barrier() {
    __asm__ __volatile__("" ::: "memory");
    __builtin_amdgcn_s_waitcnt(0xC07F);
    __builtin_amdgcn_s_barrier();
    __asm__ __volatile__("" ::: "memory");
}

// tanh via exp2 with folded constant: tanh(x) = 1 - 2/(1 + 2^(x*2*log2 e)).
__device__ __forceinline__ float fast_tanh(float x) {
#if __has_builtin(__builtin_amdgcn_exp2f) && __has_builtin(__builtin_amdgcn_rcpf)
    float e = __builtin_amdgcn_exp2f(x * 2.8853900818f);   // e^(2x)
    float r = __builtin_amdgcn_rcpf(e + 1.0f);
    return fmaf(-2.0f, r, 1.0f);
#else
    float e = __expf(2.0f * x);
    return 1.0f - __fdividef(2.0f, e + 1.0f);
#endif
}

__device__ __forceinline__ float dpp_xor1(float x) {
    return __builtin_bit_cast(float, __builtin_amdgcn_mov_dpp(
        __builtin_bit_cast(int, x), 0xB1, 0xF, 0xF, false));
}
__device__ __forceinline__ float dpp_xor2(float x) {
    return __builtin_bit_cast(float, __builtin_amdgcn_mov_dpp(
        __builtin_bit_cast(int, x), 0x4E, 0xF, 0xF, false));
}

// Acquire-poll until flag reaches 2 (both N-half producers done).
// Bounded: ~0.25 s at the 100 MHz constant clock (normal wait is ~30 us).
// On timeout we proceed: a sync bug then shows as a correctness failure,
// never a hung container.
__device__ __forceinline__ void wait_flag(const int* f) {
    long long t0 = __builtin_amdgcn_s_memrealtime();
    while (__hip_atomic_load(f, __ATOMIC_ACQUIRE, __HIP_MEMORY_SCOPE_AGENT) != 2) {
        __builtin_amdgcn_s_sleep(8);
        if (__builtin_amdgcn_s_memrealtime() - t0 > 25000000LL) break;
    }
}

__global__ void zero_flags(int* flags) { flags[threadIdx.x] = 0; }

// ---------------------------------------------------------------------------
// GEMM tile body, shared by the fused worker path and the fallback kernel.
// xw[m][n] = sum_k x[m][k]*Wxw[n][k] + Wxb[n]; 128x128 tile, 8x8/thread.
// ---------------------------------------------------------------------------
#define TM 128
#define TN 128
#define TK 32
#define LDP (TM + 4)

__device__ __forceinline__ void gemm_tile(
    const float* __restrict__ x, const float* __restrict__ Wxw,
    const float* __restrict__ Wxb, float* __restrict__ out,
    float (*As)[LDP], float (*Bs)[LDP], int t, int m0, int n0)
{
    const int lr = t >> 3;    // 0..31
    const int lc = t & 7;     // 0..7
    const int tn = t & 15, tm = t >> 4;

    float acc[8][8] = {};
    float bias[8];
#pragma unroll
    for (int jj = 0; jj < 4; ++jj) {
        bias[jj]     = Wxb[n0 + 4 * tn + jj];
        bias[4 + jj] = Wxb[n0 + 64 + 4 * tn + jj];
    }

    float4 va[4], vb[4];
#pragma unroll
    for (int hh = 0; hh < 4; ++hh) {             // prologue: kt=0
        const int m = lr + 32 * hh;
        va[hh] = *(const float4*)(x   + (size_t)(m0 + m) * I + 4 * lc);
        vb[hh] = *(const float4*)(Wxw + (size_t)(n0 + m) * I + 4 * lc);
    }

    for (int kt = 0; kt < I; kt += TK) {
#pragma unroll
        for (int hh = 0; hh < 4; ++hh) {         // regs -> LDS (transpose)
            const int m = lr + 32 * hh;
            float4 v = va[hh];
            As[4 * lc + 0][m] = v.x; As[4 * lc + 1][m] = v.y;
            As[4 * lc + 2][m] = v.z; As[4 * lc + 3][m] = v.w;
            float4 wv = vb[hh];
            Bs[4 * lc + 0][m] = wv.x; Bs[4 * lc + 1][m] = wv.y;
            Bs[4 * lc + 2][m] = wv.z; Bs[4 * lc + 3][m] = wv.w;
        }
        lds_barrier();
        if (kt + TK < I) {                       // prefetch kt+1
#pragma unroll
            for (int hh = 0; hh < 4; ++hh) {
                const int m = lr + 32 * hh;
                va[hh] = *(const float4*)(x   + (size_t)(m0 + m) * I + kt + TK + 4 * lc);
                vb[hh] = *(const float4*)(Wxw + (size_t)(n0 + m) * I + kt + TK + 4 * lc);
            }
        }
#pragma unroll
        for (int k = 0; k < TK; ++k) {
            float4 a0 = *(const float4*)&As[k][4 * tm];
            float4 a1 = *(const float4*)&As[k][4 * tm + 64];
            float4 b0 = *(const float4*)&Bs[k][4 * tn];
            float4 b1 = *(const float4*)&Bs[k][4 * tn + 64];
            float av[8] = {a0.x, a0.y, a0.z, a0.w, a1.x, a1.y, a1.z, a1.w};
            float bv[8] = {b0.x, b0.y, b0.z, b0.w, b1.x, b1.y, b1.z, b1.w};
#pragma unroll
            for (int i2 = 0; i2 < 8; ++i2)
#pragma unroll
                for (int jj = 0; jj < 8; ++jj)
                    acc[i2][jj] = fmaf(av[i2], bv[jj], acc[i2][jj]);
        }
        lds_barrier();
    }
#pragma unroll
    for (int hi = 0; hi < 2; ++hi) {
#pragma unroll
        for (int i2 = 0; i2 < 4; ++i2) {
            const int r = m0 + 64 * hi + 4 * tm + i2;
            float4 v0 = { acc[4 * hi + i2][0] + bias[0], acc[4 * hi + i2][1] + bias[1],
                          acc[4 * hi + i2][2] + bias[2], acc[4 * hi + i2][3] + bias[3] };
            float4 v1 = { acc[4 * hi + i2][4] + bias[4], acc[4 * hi + i2][5] + bias[5],
                          acc[4 * hi + i2][6] + bias[6], acc[4 * hi + i2][7] + bias[7] };
            *(float4*)(out + (size_t)r * H + n0 + 4 * tn)      = v0;
            *(float4*)(out + (size_t)r * H + n0 + 64 + 4 * tn) = v1;
        }
    }
}

// ---------------------------------------------------------------------------
// RNN recurrence body (bit-identical to R6 phase2). flags == nullptr means
// "xw fully materialized, no gating" (fallback path).
// ---------------------------------------------------------------------------
__device__ __forceinline__ void rnn_body(
    const float* __restrict__ Whw, float* __restrict__ out,
    _Float16 (*hsh)[4][72], int b, int t, const int* flags)
{
    const int w = t >> 6;        // wave: rows [64w, 64w+64)
    const int l = t & 63;
    const int j = l >> 2;        // quad: rows 64w+4j .. 64w+4j+3
    const int q = l & 3;         // k-quarter: k in [64q, 64q+64)

    // wreg[i][m] = W[64w+4j+(q^i)][64q + 2m .. 2m+1] as h2 (permuted rows).
    h2 wreg[4][32];
#pragma unroll
    for (int i = 0; i < 4; ++i) {
        const float4* wp =
            (const float4*)(Whw + (size_t)(64 * w + 4 * j + (q ^ i)) * H + 64 * q);
#pragma unroll
        for (int m = 0; m < 16; ++m) {
            float4 f = wp[m];
            wreg[i][2 * m]     = h2{(_Float16)f.x, (_Float16)f.y};
            wreg[i][2 * m + 1] = h2{(_Float16)f.z, (_Float16)f.w};
        }
    }
#pragma unroll
    for (int i = 0; i < 4; ++i)
#pragma unroll
        for (int m = 0; m < 32; ++m) {
            unsigned tmp = __builtin_bit_cast(unsigned, wreg[i][m]);
            __asm__("" : "+v"(tmp));
            wreg[i][m] = __builtin_bit_cast(h2, tmp);
        }

    hsh[0][w][l] = (_Float16)0.0f;
    __syncthreads();

    if (flags) {                        // gate initial xw reads on chunk 0
        if (t == 0) wait_flag(flags + 0);
        __syncthreads();
    }

    float* outb = out + (size_t)b * S * H + t;
    float*       op = outb;
    const float* lp = outb + 2 * (size_t)H;
    float xw0 = outb[0], xw1 = outb[(size_t)H];

    float hv = 0.f;
#pragma unroll 2
    for (int s = 0; s < S; ++s) {
        const int p = s & 1;
        if (flags && ((s + 2) & 127) == 0 && s + 2 < S) {
            if (t == 0) wait_flag(flags + ((s + 2) >> 7));
            __syncthreads();            // broadcast t0's acquire to the block
        }
        float xwn = lp[0]; lp += H;     // prefetch xw for step s+2

        const uint4* hp = (const uint4*)&hsh[p][q][0];
        float acc0 = 0.f, acc1 = 0.f, acc2 = 0.f, acc3 = 0.f;
#pragma unroll
        for (int u = 0; u < 8; ++u) {
            uint4 v = hp[u];
            h2 q0 = __builtin_bit_cast(h2, v.x);
            h2 q1 = __builtin_bit_cast(h2, v.y);
            h2 q2 = __builtin_bit_cast(h2, v.z);
            h2 q3 = __builtin_bit_cast(h2, v.w);
            acc0 = fdot2(wreg[0][4 * u + 0], q0, acc0);
            acc0 = fdot2(wreg[0][4 * u + 1], q1, acc0);
            acc0 = fdot2(wreg[0][4 * u + 2], q2, acc0);
            acc0 = fdot2(wreg[0][4 * u + 3], q3, acc0);
            acc1 = fdot2(wreg[1][4 * u + 0], q0, acc1);
            acc1 = fdot2(wreg[1][4 * u + 1], q1, acc1);
            acc1 = fdot2(wreg[1][4 * u + 2], q2, acc1);
            acc1 = fdot2(wreg[1][4 * u + 3], q3, acc1);
            acc2 = fdot2(wreg[2][4 * u + 0], q0, acc2);
            acc2 = fdot2(wreg[2][4 * u + 1], q1, acc2);
            acc2 = fdot2(wreg[2][4 * u + 2], q2, acc2);
            acc2 = fdot2(wreg[2][4 * u + 3], q3, acc2);
            acc3 = fdot2(wreg[3][4 * u + 0], q0, acc3);
            acc3 = fdot2(wreg[3][4 * u + 1], q1, acc3);
            acc3 = fdot2(wreg[3][4 * u + 2], q2, acc3);
            acc3 = fdot2(wreg[3][4 * u + 3], q3, acc3);
        }

        // Select-free quad butterfly (rows pre-permuted by q^i):
        float Sa  = acc0 + dpp_xor1(acc1);
        float Sb  = acc2 + dpp_xor1(acc3);
        float sum = Sa + dpp_xor2(Sb);       // full sum for row 64w+l == t

        hv = fast_tanh(xw0 + sum);
        hsh[p ^ 1][w][l] = (_Float16)hv;      // publish first (lgkm path)
        op[0] = hv; op += H;                  // outputs[b,s,t] (vm path)

        lds_barrier();                        // the ONE barrier per step

        xw0 = xw1; xw1 = xwn;
    }
    out[(size_t)B * S * H + (size_t)b * H + t] = hv;   // h_last
}

// ---------------------------------------------------------------------------
// Fused persistent kernel, grid = 256 blocks (one per CU).
//   blocks 0..223   : GEMM workers (dispatched FIRST; never wait on anyone ->
//                     unconditional forward progress, deadlock-free)
//   blocks 224..255 : RNN (batch = bid-224), t0 acquire-polls chunk flags
// Workers produce one (all-batch, 128-step) chunk in ~25us; RNN consumes one
// per ~52us -> producers stay ahead after a one-time ~25us startup stall.
// ---------------------------------------------------------------------------
__global__ __launch_bounds__(256, 1) void fused_srnn(
    const float* __restrict__ x, const float* __restrict__ Wxw,
    const float* __restrict__ Wxb, const float* __restrict__ Whw,
    float* __restrict__ out, int* __restrict__ flags)
{
    __shared__ __align__(16) float As[TK][LDP];
    __shared__ __align__(16) float Bs[TK][LDP];
    __shared__ __align__(16) _Float16 hsh[2][4][72];

    const int bid = blockIdx.x;
    const int t   = threadIdx.x;

    if (bid < NWORK) {
        for (int tau = bid; tau < NTILE; tau += NWORK) {
            // s-major order: tau = st*64 + bb*2 + nt
            const int st = tau >> 6;
            const int bb = (tau >> 1) & 31;
            const int nt = tau & 1;
            gemm_tile(x, Wxw, Wxb, out, As, Bs, t,
                      bb * S + st * TM, nt * TN);
            // publish this (batch, s-chunk) half: fence own stores, sync, add.
            __threadfence();
            __syncthreads();
            if (t == 0)
                __hip_atomic_fetch_add(&flags[bb * 16 + st], 1,
                                       __ATOMIC_RELEASE, __HIP_MEMORY_SCOPE_AGENT);
        }
        return;
    }
    rnn_body(Whw, out, hsh, bid - NWORK, t, flags + (bid - NWORK) * 16);
}

// ---------------------------------------------------------------------------
// Fallback path (no workspace): the proven R6 two-kernel pipeline.
// ---------------------------------------------------------------------------
__global__ __launch_bounds__(256) void phase1_gemm(
    const float* __restrict__ x, const float* __restrict__ Wxw,
    const float* __restrict__ Wxb, float* __restrict__ out)
{
    __shared__ __align__(16) float As[TK][LDP];
    __shared__ __align__(16) float Bs[TK][LDP];
    gemm_tile(x, Wxw, Wxb, out, As, Bs, threadIdx.x,
              blockIdx.x * TM, blockIdx.y * TN);
}

__global__ __launch_bounds__(256, 1) void phase2_rnn(
    const float* __restrict__ Whw, float* __restrict__ out)
{
    __shared__ __align__(16) _Float16 hsh[2][4][72];
    rnn_body(Whw, out, hsh, blockIdx.x, threadIdx.x, nullptr);
}

// ---------------------------------------------------------------------------
extern "C" void kernel_launch(void* const* d_in, const int* in_sizes, int n_in,
                              void* d_out, int out_size, void* d_ws, size_t ws_size,
                              hipStream_t stream) {
    const float* x   = (const float*)d_in[0];
    const float* Wxw = (const float*)d_in[1];
    const float* Wxb = (const float*)d_in[2];
    const float* Whw = (const float*)d_in[3];
    float* out = (float*)d_out;

    if (d_ws != nullptr && ws_size >= NFLAG * sizeof(int)) {
        int* flags = (int*)d_ws;
        zero_flags<<<1, NFLAG, 0, stream>>>(flags);
        fused_srnn<<<NWORK + NRNN, 256, 0, stream>>>(x, Wxw, Wxb, Whw, out, flags);
    } else {
        dim3 g1(B * S / TM, H / TN);   // 512 x 2
        phase1_gemm<<<g1, 256, 0, stream>>>(x, Wxw, Wxb, out);
        phase2_rnn<<<B, 256, 0, stream>>>(Whw, out);
    }
}

// Round 10
// 998.043 us; speedup vs baseline: 1.0807x; 1.0807x over previous
//
#include <hip/hip_runtime.h>

#define B 32
#define S 2048
#define I 256
#define H 256

#define NWORK  224    // GEMM worker blocks (dispatched FIRST: bid 0..223)
#define NRNN   32     // RNN blocks (bid 224..255), one per batch
#define NTILE  1024   // 512 M-tiles x 2 N-tiles
#define NFLAG  512    // 32 batches x 16 s-chunks
#define PFD    8      // xw prefetch depth (steps); 8*H past end stays in-bounds

typedef _Float16 h2 __attribute__((ext_vector_type(2)));
typedef float    f4 __attribute__((ext_vector_type(4)));   // native vec for NT builtins

__device__ __forceinline__ float fdot2(h2 a, h2 b, float c) {
#if __has_builtin(__builtin_amdgcn_fdot2)
    return __builtin_amdgcn_fdot2(a, b, c, false);
#else
    return fmaf((float)a[1], (float)b[1], fmaf((float)a[0], (float)b[0], c));
#endif
}

// NT store of a float4 through the native-vector builtin.
__device__ __forceinline__ void nt_store4(float* p, float4 v) {
    __builtin_nontemporal_store(__builtin_bit_cast(f4, v), (f4*)p);
}

// lgkm-only workgroup barrier. imm 0xC07F = vmcnt(63) expcnt(7) lgkmcnt(0).
__device__ __forceinline__ void lds_barrier() {
    __asm__ __volatile__("" ::: "memory");
    __builtin_amdgcn_s_waitcnt(0xC07F);
    __builtin_amdgcn_s_barrier();
    __asm__ __volatile__("" ::: "memory");
}

// tanh via exp2 with folded constant: tanh(x) = 1 - 2/(1 + 2^(x*2*log2 e)).
__device__ __forceinline__ float fast_tanh(float x) {
#if __has_builtin(__builtin_amdgcn_exp2f) && __has_builtin(__builtin_amdgcn_rcpf)
    float e = __builtin_amdgcn_exp2f(x * 2.8853900818f);   // e^(2x)
    float r = __builtin_amdgcn_rcpf(e + 1.0f);
    return fmaf(-2.0f, r, 1.0f);
#else
    float e = __expf(2.0f * x);
    return 1.0f - __fdividef(2.0f, e + 1.0f);
#endif
}

__device__ __forceinline__ float dpp_xor1(float x) {
    return __builtin_bit_cast(float, __builtin_amdgcn_mov_dpp(
        __builtin_bit_cast(int, x), 0xB1, 0xF, 0xF, false));
}
__device__ __forceinline__ float dpp_xor2(float x) {
    return __builtin_bit_cast(float, __builtin_amdgcn_mov_dpp(
        __builtin_bit_cast(int, x), 0x4E, 0xF, 0xF, false));
}

// Acquire-poll until flag reaches 2 (both N-half producers done).
// Bounded (~0.25 s at the 100 MHz constant clock; normal wait ~30 us): a
// sync bug shows as a correctness failure, never a hung container.
__device__ __forceinline__ void wait_flag(const int* f) {
    long long t0 = __builtin_amdgcn_s_memrealtime();
    while (__hip_atomic_load(f, __ATOMIC_ACQUIRE, __HIP_MEMORY_SCOPE_AGENT) != 2) {
        __builtin_amdgcn_s_sleep(8);
        if (__builtin_amdgcn_s_memrealtime() - t0 > 25000000LL) break;
    }
}

__global__ void zero_flags(int* flags) { flags[threadIdx.x] = 0; }

// ---------------------------------------------------------------------------
// GEMM tile body. xw[m][n] = sum_k x[m][k]*Wxw[n][k] + Wxb[n].
// 128x128 tile, 8x8/thread. NONTEMPORAL xw stores -- the consumer is on
// another XCD; dirty-remote-L2 reads are the fused path's latency killer.
// NT stores push lines to memory clean (and skip write-allocate pollution).
// ---------------------------------------------------------------------------
#define TM 128
#define TN 128
#define TK 32
#define LDP (TM + 4)

__device__ __forceinline__ void gemm_tile(
    const float* __restrict__ x, const float* __restrict__ Wxw,
    const float* __restrict__ Wxb, float* __restrict__ out,
    float (*As)[LDP], float (*Bs)[LDP], int t, int m0, int n0)
{
    const int lr = t >> 3;    // 0..31
    const int lc = t & 7;     // 0..7
    const int tn = t & 15, tm = t >> 4;

    float acc[8][8] = {};
    float bias[8];
#pragma unroll
    for (int jj = 0; jj < 4; ++jj) {
        bias[jj]     = Wxb[n0 + 4 * tn + jj];
        bias[4 + jj] = Wxb[n0 + 64 + 4 * tn + jj];
    }

    float4 va[4], vb[4];
#pragma unroll
    for (int hh = 0; hh < 4; ++hh) {             // prologue: kt=0
        const int m = lr + 32 * hh;
        va[hh] = *(const float4*)(x   + (size_t)(m0 + m) * I + 4 * lc);
        vb[hh] = *(const float4*)(Wxw + (size_t)(n0 + m) * I + 4 * lc);
    }

    for (int kt = 0; kt < I; kt += TK) {
#pragma unroll
        for (int hh = 0; hh < 4; ++hh) {         // regs -> LDS (transpose)
            const int m = lr + 32 * hh;
            float4 v = va[hh];
            As[4 * lc + 0][m] = v.x; As[4 * lc + 1][m] = v.y;
            As[4 * lc + 2][m] = v.z; As[4 * lc + 3][m] = v.w;
            float4 wv = vb[hh];
            Bs[4 * lc + 0][m] = wv.x; Bs[4 * lc + 1][m] = wv.y;
            Bs[4 * lc + 2][m] = wv.z; Bs[4 * lc + 3][m] = wv.w;
        }
        lds_barrier();
        if (kt + TK < I) {                       // prefetch kt+1
#pragma unroll
            for (int hh = 0; hh < 4; ++hh) {
                const int m = lr + 32 * hh;
                va[hh] = *(const float4*)(x   + (size_t)(m0 + m) * I + kt + TK + 4 * lc);
                vb[hh] = *(const float4*)(Wxw + (size_t)(n0 + m) * I + kt + TK + 4 * lc);
            }
        }
#pragma unroll
        for (int k = 0; k < TK; ++k) {
            float4 a0 = *(const float4*)&As[k][4 * tm];
            float4 a1 = *(const float4*)&As[k][4 * tm + 64];
            float4 b0 = *(const float4*)&Bs[k][4 * tn];
            float4 b1 = *(const float4*)&Bs[k][4 * tn + 64];
            float av[8] = {a0.x, a0.y, a0.z, a0.w, a1.x, a1.y, a1.z, a1.w};
            float bv[8] = {b0.x, b0.y, b0.z, b0.w, b1.x, b1.y, b1.z, b1.w};
#pragma unroll
            for (int i2 = 0; i2 < 8; ++i2)
#pragma unroll
                for (int jj = 0; jj < 8; ++jj)
                    acc[i2][jj] = fmaf(av[i2], bv[jj], acc[i2][jj]);
        }
        lds_barrier();
    }
#pragma unroll
    for (int hi = 0; hi < 2; ++hi) {
#pragma unroll
        for (int i2 = 0; i2 < 4; ++i2) {
            const int r = m0 + 64 * hi + 4 * tm + i2;
            float4 v0 = { acc[4 * hi + i2][0] + bias[0], acc[4 * hi + i2][1] + bias[1],
                          acc[4 * hi + i2][2] + bias[2], acc[4 * hi + i2][3] + bias[3] };
            float4 v1 = { acc[4 * hi + i2][4] + bias[4], acc[4 * hi + i2][5] + bias[5],
                          acc[4 * hi + i2][6] + bias[6], acc[4 * hi + i2][7] + bias[7] };
            nt_store4(out + (size_t)r * H + n0 + 4 * tn,      v0);
            nt_store4(out + (size_t)r * H + n0 + 64 + 4 * tn, v1);
        }
    }
}

// ---------------------------------------------------------------------------
// RNN recurrence body. Math bit-identical to R6/R8. flags==nullptr: no gating.
// PFD=8 xw prefetch ring (static indices via unroll-8) -- 3.2 us of latency
// slack covers loaded-HBM/coherence latency during worker co-run.
// NT store for out (write-once, no reader on this XCD).
// ---------------------------------------------------------------------------
__device__ __forceinline__ void rnn_body(
    const float* __restrict__ Whw, float* __restrict__ out,
    _Float16 (*hsh)[4][72], int b, int t, const int* flags)
{
    const int w = t >> 6;        // wave: rows [64w, 64w+64)
    const int l = t & 63;
    const int j = l >> 2;        // quad: rows 64w+4j .. 64w+4j+3
    const int q = l & 3;         // k-quarter: k in [64q, 64q+64)

    // wreg[i][m] = W[64w+4j+(q^i)][64q + 2m .. 2m+1] as h2 (permuted rows).
    h2 wreg[4][32];
#pragma unroll
    for (int i = 0; i < 4; ++i) {
        const float4* wp =
            (const float4*)(Whw + (size_t)(64 * w + 4 * j + (q ^ i)) * H + 64 * q);
#pragma unroll
        for (int m = 0; m < 16; ++m) {
            float4 f = wp[m];
            wreg[i][2 * m]     = h2{(_Float16)f.x, (_Float16)f.y};
            wreg[i][2 * m + 1] = h2{(_Float16)f.z, (_Float16)f.w};
        }
    }
#pragma unroll
    for (int i = 0; i < 4; ++i)
#pragma unroll
        for (int m = 0; m < 32; ++m) {
            unsigned tmp = __builtin_bit_cast(unsigned, wreg[i][m]);
            __asm__("" : "+v"(tmp));
            wreg[i][m] = __builtin_bit_cast(h2, tmp);
        }

    hsh[0][w][l] = (_Float16)0.0f;
    __syncthreads();

    if (flags) {                        // gate initial xw reads on chunk 0
        if (t == 0) wait_flag(flags + 0);
        __syncthreads();
    }

    float* outb = out + (size_t)b * S * H + t;
    float* op = outb;

    // PFD-deep xw ring. Reads up to PFD steps past the end land in the
    // h_last region / its tail (in bounds for all b; values unused).
    float xr[PFD];
#pragma unroll
    for (int i = 0; i < PFD; ++i) xr[i] = outb[(size_t)i * H];
    const float* lp = outb + (size_t)PFD * H;

    float hv = 0.f;
#pragma unroll PFD
    for (int s = 0; s < S; ++s) {
        const int p  = s & 1;            // static under unroll (PFD even)
        const int rp = s & (PFD - 1);    // static ring slot
        if (flags && ((s + PFD) & 127) == 0 && s + PFD < S) {
            if (t == 0) wait_flag(flags + ((s + PFD) >> 7));
            __syncthreads();             // broadcast t0's acquire to the block
        }
        float xw0 = xr[rp];

        const uint4* hp = (const uint4*)&hsh[p][q][0];
        float acc0 = 0.f, acc1 = 0.f, acc2 = 0.f, acc3 = 0.f;
#pragma unroll
        for (int u = 0; u < 8; ++u) {
            uint4 v = hp[u];
            h2 q0 = __builtin_bit_cast(h2, v.x);
            h2 q1 = __builtin_bit_cast(h2, v.y);
            h2 q2 = __builtin_bit_cast(h2, v.z);
            h2 q3 = __builtin_bit_cast(h2, v.w);
            acc0 = fdot2(wreg[0][4 * u + 0], q0, acc0);
            acc0 = fdot2(wreg[0][4 * u + 1], q1, acc0);
            acc0 = fdot2(wreg[0][4 * u + 2], q2, acc0);
            acc0 = fdot2(wreg[0][4 * u + 3], q3, acc0);
            acc1 = fdot2(wreg[1][4 * u + 0], q0, acc1);
            acc1 = fdot2(wreg[1][4 * u + 1], q1, acc1);
            acc1 = fdot2(wreg[1][4 * u + 2], q2, acc1);
            acc1 = fdot2(wreg[1][4 * u + 3], q3, acc1);
            acc2 = fdot2(wreg[2][4 * u + 0], q0, acc2);
            acc2 = fdot2(wreg[2][4 * u + 1], q1, acc2);
            acc2 = fdot2(wreg[2][4 * u + 2], q2, acc2);
            acc2 = fdot2(wreg[2][4 * u + 3], q3, acc2);
            acc3 = fdot2(wreg[3][4 * u + 0], q0, acc3);
            acc3 = fdot2(wreg[3][4 * u + 1], q1, acc3);
            acc3 = fdot2(wreg[3][4 * u + 2], q2, acc3);
            acc3 = fdot2(wreg[3][4 * u + 3], q3, acc3);
        }

        // Select-free quad butterfly (rows pre-permuted by q^i):
        float Sa  = acc0 + dpp_xor1(acc1);
        float Sb  = acc2 + dpp_xor1(acc3);
        float sum = Sa + dpp_xor2(Sb);       // full sum for row 64w+l == t

        hv = fast_tanh(xw0 + sum);
        hsh[p ^ 1][w][l] = (_Float16)hv;          // publish first (lgkm path)
        __builtin_nontemporal_store(hv, op);      // outputs[b,s,t]
        op += H;
        xr[rp] = lp[0]; lp += H;                  // refill ring: step s+PFD

        lds_barrier();                            // the ONE barrier per step
    }
    out[(size_t)B * S * H + (size_t)b * H + t] = hv;   // h_last
}

// ---------------------------------------------------------------------------
// Fused persistent kernel, grid = 256 blocks (one per CU).
//   blocks 0..223   : GEMM workers (dispatched first; never wait -> no deadlock)
//   blocks 224..255 : RNN (batch = bid-224), t0 acquire-polls chunk flags
// ---------------------------------------------------------------------------
__global__ __launch_bounds__(256, 1) void fused_srnn(
    const float* __restrict__ x, const float* __restrict__ Wxw,
    const float* __restrict__ Wxb, const float* __restrict__ Whw,
    float* __restrict__ out, int* __restrict__ flags)
{
    __shared__ __align__(16) float As[TK][LDP];
    __shared__ __align__(16) float Bs[TK][LDP];
    __shared__ __align__(16) _Float16 hsh[2][4][72];

    const int bid = blockIdx.x;
    const int t   = threadIdx.x;

    if (bid < NWORK) {
        for (int tau = bid; tau < NTILE; tau += NWORK) {
            // s-major order: tau = st*64 + bb*2 + nt
            const int st = tau >> 6;
            const int bb = (tau >> 1) & 31;
            const int nt = tau & 1;
            gemm_tile(x, Wxw, Wxb, out, As, Bs, t,
                      bb * S + st * TM, nt * TN);
            // publish this (batch, s-chunk) half: fence own stores, sync, add.
            __threadfence();
            __syncthreads();
            if (t == 0)
                __hip_atomic_fetch_add(&flags[bb * 16 + st], 1,
                                       __ATOMIC_RELEASE, __HIP_MEMORY_SCOPE_AGENT);
        }
        return;
    }
    rnn_body(Whw, out, hsh, bid - NWORK, t, flags + (bid - NWORK) * 16);
}

// ---------------------------------------------------------------------------
// Fallback path (no workspace): the proven two-kernel pipeline.
// ---------------------------------------------------------------------------
__global__ __launch_bounds__(256) void phase1_gemm(
    const float* __restrict__ x, const float* __restrict__ Wxw,
    const float* __restrict__ Wxb, float* __restrict__ out)
{
    __shared__ __align__(16) float As[TK][LDP];
    __shared__ __align__(16) float Bs[TK][LDP];
    gemm_tile(x, Wxw, Wxb, out, As, Bs, threadIdx.x,
              blockIdx.x * TM, blockIdx.y * TN);
}

__global__ __launch_bounds__(256, 1) void phase2_rnn(
    const float* __restrict__ Whw, float* __restrict__ out)
{
    __shared__ __align__(16) _Float16 hsh[2][4][72];
    rnn_body(Whw, out, hsh, blockIdx.x, threadIdx.x, nullptr);
}

// ---------------------------------------------------------------------------
extern "C" void kernel_launch(void* const* d_in, const int* in_sizes, int n_in,
                              void* d_out, int out_size, void* d_ws, size_t ws_size,
                              hipStream_t stream) {
    const float* x   = (const float*)d_in[0];
    const float* Wxw = (const float*)d_in[1];
    const float* Wxb = (const float*)d_in[2];
    const float* Whw = (const float*)d_in[3];
    float* out = (float*)d_out;

    if (d_ws != nullptr && ws_size >= NFLAG * sizeof(int)) {
        int* flags = (int*)d_ws;
        zero_flags<<<1, NFLAG, 0, stream>>>(flags);
        fused_srnn<<<NWORK + NRNN, 256, 0, stream>>>(x, Wxw, Wxb, Whw, out, flags);
    } else {
        dim3 g1(B * S / TM, H / TN);   // 512 x 2
        phase1_gemm<<<g1, 256, 0, stream>>>(x, Wxw, Wxb, out);
        phase2_rnn<<<B, 256, 0, stream>>>(Whw, out);
    }
}

// Round 11
// 960.494 us; speedup vs baseline: 1.1229x; 1.0391x over previous
//
#include <hip/hip_runtime.h>

#define B 32
#define S 2048
#define I 256
#define H 256

#define NWORK  128    // GEMM worker blocks (bid 0..127). 128 is 3x ahead of
                      // RNN demand; fewer dense-FMA CUs -> less clock throttle.
#define NRNN   32     // RNN blocks (bid 128..159), one per batch
#define NTILE  1024   // 512 M-tiles x 2 N-tiles
#define NFLAG  512    // 32 batches x 16 s-chunks
#define PFD    8      // xw prefetch depth (steps); 8*H past end stays in-bounds

typedef _Float16 h2 __attribute__((ext_vector_type(2)));
typedef float    f4 __attribute__((ext_vector_type(4)));   // native vec for NT builtins

__device__ __forceinline__ float fdot2(h2 a, h2 b, float c) {
#if __has_builtin(__builtin_amdgcn_fdot2)
    return __builtin_amdgcn_fdot2(a, b, c, false);
#else
    return fmaf((float)a[1], (float)b[1], fmaf((float)a[0], (float)b[0], c));
#endif
}

// NT store of a float4 through the native-vector builtin.
__device__ __forceinline__ void nt_store4(float* p, float4 v) {
    __builtin_nontemporal_store(__builtin_bit_cast(f4, v), (f4*)p);
}

// lgkm-only workgroup barrier. imm 0xC07F = vmcnt(63) expcnt(7) lgkmcnt(0).
__device__ __forceinline__ void lds_barrier() {
    __asm__ __volatile__("" ::: "memory");
    __builtin_amdgcn_s_waitcnt(0xC07F);
    __builtin_amdgcn_s_barrier();
    __asm__ __volatile__("" ::: "memory");
}

// tanh via exp2 with folded constant: tanh(x) = 1 - 2/(1 + 2^(x*2*log2 e)).
__device__ __forceinline__ float fast_tanh(float x) {
#if __has_builtin(__builtin_amdgcn_exp2f) && __has_builtin(__builtin_amdgcn_rcpf)
    float e = __builtin_amdgcn_exp2f(x * 2.8853900818f);   // e^(2x)
    float r = __builtin_amdgcn_rcpf(e + 1.0f);
    return fmaf(-2.0f, r, 1.0f);
#else
    float e = __expf(2.0f * x);
    return 1.0f - __fdividef(2.0f, e + 1.0f);
#endif
}

__device__ __forceinline__ float dpp_xor1(float x) {
    return __builtin_bit_cast(float, __builtin_amdgcn_mov_dpp(
        __builtin_bit_cast(int, x), 0xB1, 0xF, 0xF, false));
}
__device__ __forceinline__ float dpp_xor2(float x) {
    return __builtin_bit_cast(float, __builtin_amdgcn_mov_dpp(
        __builtin_bit_cast(int, x), 0x4E, 0xF, 0xF, false));
}

// Acquire-poll until flag reaches 2 (both N-half producers done).
// Bounded (~0.25 s at the 100 MHz constant clock; normal wait ~30 us): a
// sync bug shows as a correctness failure, never a hung container.
__device__ __forceinline__ void wait_flag(const int* f) {
    long long t0 = __builtin_amdgcn_s_memrealtime();
    while (__hip_atomic_load(f, __ATOMIC_ACQUIRE, __HIP_MEMORY_SCOPE_AGENT) != 2) {
        __builtin_amdgcn_s_sleep(8);
        if (__builtin_amdgcn_s_memrealtime() - t0 > 25000000LL) break;
    }
}

__global__ void zero_flags(int* flags) { flags[threadIdx.x] = 0; }

// ---------------------------------------------------------------------------
// GEMM tile body. xw[m][n] = sum_k x[m][k]*Wxw[n][k] + Wxb[n].
// 128x128 tile, 8x8/thread. NT xw stores: the consumer is on another XCD;
// push lines to memory clean, skip write-allocate pollution.
// ---------------------------------------------------------------------------
#define TM 128
#define TN 128
#define TK 32
#define LDP (TM + 4)

__device__ __forceinline__ void gemm_tile(
    const float* __restrict__ x, const float* __restrict__ Wxw,
    const float* __restrict__ Wxb, float* __restrict__ out,
    float (*As)[LDP], float (*Bs)[LDP], int t, int m0, int n0)
{
    const int lr = t >> 3;    // 0..31
    const int lc = t & 7;     // 0..7
    const int tn = t & 15, tm = t >> 4;

    float acc[8][8] = {};
    float bias[8];
#pragma unroll
    for (int jj = 0; jj < 4; ++jj) {
        bias[jj]     = Wxb[n0 + 4 * tn + jj];
        bias[4 + jj] = Wxb[n0 + 64 + 4 * tn + jj];
    }

    float4 va[4], vb[4];
#pragma unroll
    for (int hh = 0; hh < 4; ++hh) {             // prologue: kt=0
        const int m = lr + 32 * hh;
        va[hh] = *(const float4*)(x   + (size_t)(m0 + m) * I + 4 * lc);
        vb[hh] = *(const float4*)(Wxw + (size_t)(n0 + m) * I + 4 * lc);
    }

    for (int kt = 0; kt < I; kt += TK) {
#pragma unroll
        for (int hh = 0; hh < 4; ++hh) {         // regs -> LDS (transpose)
            const int m = lr + 32 * hh;
            float4 v = va[hh];
            As[4 * lc + 0][m] = v.x; As[4 * lc + 1][m] = v.y;
            As[4 * lc + 2][m] = v.z; As[4 * lc + 3][m] = v.w;
            float4 wv = vb[hh];
            Bs[4 * lc + 0][m] = wv.x; Bs[4 * lc + 1][m] = wv.y;
            Bs[4 * lc + 2][m] = wv.z; Bs[4 * lc + 3][m] = wv.w;
        }
        lds_barrier();
        if (kt + TK < I) {                       // prefetch kt+1
#pragma unroll
            for (int hh = 0; hh < 4; ++hh) {
                const int m = lr + 32 * hh;
                va[hh] = *(const float4*)(x   + (size_t)(m0 + m) * I + kt + TK + 4 * lc);
                vb[hh] = *(const float4*)(Wxw + (size_t)(n0 + m) * I + kt + TK + 4 * lc);
            }
        }
#pragma unroll
        for (int k = 0; k < TK; ++k) {
            float4 a0 = *(const float4*)&As[k][4 * tm];
            float4 a1 = *(const float4*)&As[k][4 * tm + 64];
            float4 b0 = *(const float4*)&Bs[k][4 * tn];
            float4 b1 = *(const float4*)&Bs[k][4 * tn + 64];
            float av[8] = {a0.x, a0.y, a0.z, a0.w, a1.x, a1.y, a1.z, a1.w};
            float bv[8] = {b0.x, b0.y, b0.z, b0.w, b1.x, b1.y, b1.z, b1.w};
#pragma unroll
            for (int i2 = 0; i2 < 8; ++i2)
#pragma unroll
                for (int jj = 0; jj < 8; ++jj)
                    acc[i2][jj] = fmaf(av[i2], bv[jj], acc[i2][jj]);
        }
        lds_barrier();
    }
#pragma unroll
    for (int hi = 0; hi < 2; ++hi) {
#pragma unroll
        for (int i2 = 0; i2 < 4; ++i2) {
            const int r = m0 + 64 * hi + 4 * tm + i2;
            float4 v0 = { acc[4 * hi + i2][0] + bias[0], acc[4 * hi + i2][1] + bias[1],
                          acc[4 * hi + i2][2] + bias[2], acc[4 * hi + i2][3] + bias[3] };
            float4 v1 = { acc[4 * hi + i2][4] + bias[4], acc[4 * hi + i2][5] + bias[5],
                          acc[4 * hi + i2][6] + bias[6], acc[4 * hi + i2][7] + bias[7] };
            nt_store4(out + (size_t)r * H + n0 + 4 * tn,      v0);
            nt_store4(out + (size_t)r * H + n0 + 64 + 4 * tn, v1);
        }
    }
}

// ---------------------------------------------------------------------------
// RNN recurrence body. Math bit-identical to R6/R8. flags==nullptr: no gating.
// PFD=8 xw prefetch ring (static indices via unroll-8). Output stores are
// NORMAL (R11): NT scalar stores complete slowly (bypass L2) and pile toward
// the 63-deep vmcnt cap at 1 store+1 load per ~400ns step -> issue stalls.
// L2-completing stores keep the VM queue shallow.
// ---------------------------------------------------------------------------
__device__ __forceinline__ void rnn_body(
    const float* __restrict__ Whw, float* __restrict__ out,
    _Float16 (*hsh)[4][72], int b, int t, const int* flags)
{
    const int w = t >> 6;        // wave: rows [64w, 64w+64)
    const int l = t & 63;
    const int j = l >> 2;        // quad: rows 64w+4j .. 64w+4j+3
    const int q = l & 3;         // k-quarter: k in [64q, 64q+64)

    // wreg[i][m] = W[64w+4j+(q^i)][64q + 2m .. 2m+1] as h2 (permuted rows).
    h2 wreg[4][32];
#pragma unroll
    for (int i = 0; i < 4; ++i) {
        const float4* wp =
            (const float4*)(Whw + (size_t)(64 * w + 4 * j + (q ^ i)) * H + 64 * q);
#pragma unroll
        for (int m = 0; m < 16; ++m) {
            float4 f = wp[m];
            wreg[i][2 * m]     = h2{(_Float16)f.x, (_Float16)f.y};
            wreg[i][2 * m + 1] = h2{(_Float16)f.z, (_Float16)f.w};
        }
    }
#pragma unroll
    for (int i = 0; i < 4; ++i)
#pragma unroll
        for (int m = 0; m < 32; ++m) {
            unsigned tmp = __builtin_bit_cast(unsigned, wreg[i][m]);
            __asm__("" : "+v"(tmp));
            wreg[i][m] = __builtin_bit_cast(h2, tmp);
        }

    hsh[0][w][l] = (_Float16)0.0f;
    __syncthreads();

    if (flags) {                        // gate initial xw reads on chunk 0
        if (t == 0) wait_flag(flags + 0);
        __syncthreads();
    }

    float* outb = out + (size_t)b * S * H + t;
    float* op = outb;

    // PFD-deep xw ring. Reads up to PFD steps past the end land in the
    // h_last region / its tail (in bounds for all b; values unused).
    float xr[PFD];
#pragma unroll
    for (int i = 0; i < PFD; ++i) xr[i] = outb[(size_t)i * H];
    const float* lp = outb + (size_t)PFD * H;

    float hv = 0.f;
#pragma unroll PFD
    for (int s = 0; s < S; ++s) {
        const int p  = s & 1;            // static under unroll (PFD even)
        const int rp = s & (PFD - 1);    // static ring slot
        if (flags && ((s + PFD) & 127) == 0 && s + PFD < S) {
            if (t == 0) wait_flag(flags + ((s + PFD) >> 7));
            __syncthreads();             // broadcast t0's acquire to the block
        }
        float xw0 = xr[rp];

        const uint4* hp = (const uint4*)&hsh[p][q][0];
        float acc0 = 0.f, acc1 = 0.f, acc2 = 0.f, acc3 = 0.f;
#pragma unroll
        for (int u = 0; u < 8; ++u) {
            uint4 v = hp[u];
            h2 q0 = __builtin_bit_cast(h2, v.x);
            h2 q1 = __builtin_bit_cast(h2, v.y);
            h2 q2 = __builtin_bit_cast(h2, v.z);
            h2 q3 = __builtin_bit_cast(h2, v.w);
            acc0 = fdot2(wreg[0][4 * u + 0], q0, acc0);
            acc0 = fdot2(wreg[0][4 * u + 1], q1, acc0);
            acc0 = fdot2(wreg[0][4 * u + 2], q2, acc0);
            acc0 = fdot2(wreg[0][4 * u + 3], q3, acc0);
            acc1 = fdot2(wreg[1][4 * u + 0], q0, acc1);
            acc1 = fdot2(wreg[1][4 * u + 1], q1, acc1);
            acc1 = fdot2(wreg[1][4 * u + 2], q2, acc1);
            acc1 = fdot2(wreg[1][4 * u + 3], q3, acc1);
            acc2 = fdot2(wreg[2][4 * u + 0], q0, acc2);
            acc2 = fdot2(wreg[2][4 * u + 1], q1, acc2);
            acc2 = fdot2(wreg[2][4 * u + 2], q2, acc2);
            acc2 = fdot2(wreg[2][4 * u + 3], q3, acc2);
            acc3 = fdot2(wreg[3][4 * u + 0], q0, acc3);
            acc3 = fdot2(wreg[3][4 * u + 1], q1, acc3);
            acc3 = fdot2(wreg[3][4 * u + 2], q2, acc3);
            acc3 = fdot2(wreg[3][4 * u + 3], q3, acc3);
        }

        // Select-free quad butterfly (rows pre-permuted by q^i):
        float Sa  = acc0 + dpp_xor1(acc1);
        float Sb  = acc2 + dpp_xor1(acc3);
        float sum = Sa + dpp_xor2(Sb);       // full sum for row 64w+l == t

        hv = fast_tanh(xw0 + sum);
        hsh[p ^ 1][w][l] = (_Float16)hv;     // publish first (lgkm path)
        op[0] = hv;                          // outputs[b,s,t] (normal store)
        op += H;
        xr[rp] = lp[0]; lp += H;             // refill ring: step s+PFD

        lds_barrier();                       // the ONE barrier per step
    }
    out[(size_t)B * S * H + (size_t)b * H + t] = hv;   // h_last
}

// ---------------------------------------------------------------------------
// Fused persistent kernel, grid = 160 blocks (<= 1 per CU; 96 CUs idle to
// limit power-driven clock throttle during the worker window).
//   blocks 0..127   : GEMM workers (dispatched first; never wait -> no deadlock)
//   blocks 128..159 : RNN (batch = bid-128), t0 acquire-polls chunk flags
// ---------------------------------------------------------------------------
__global__ __launch_bounds__(256, 1) void fused_srnn(
    const float* __restrict__ x, const float* __restrict__ Wxw,
    const float* __restrict__ Wxb, const float* __restrict__ Whw,
    float* __restrict__ out, int* __restrict__ flags)
{
    __shared__ __align__(16) float As[TK][LDP];
    __shared__ __align__(16) float Bs[TK][LDP];
    __shared__ __align__(16) _Float16 hsh[2][4][72];

    const int bid = blockIdx.x;
    const int t   = threadIdx.x;

    if (bid < NWORK) {
        for (int tau = bid; tau < NTILE; tau += NWORK) {
            // s-major order: tau = st*64 + bb*2 + nt
            const int st = tau >> 6;
            const int bb = (tau >> 1) & 31;
            const int nt = tau & 1;
            gemm_tile(x, Wxw, Wxb, out, As, Bs, t,
                      bb * S + st * TM, nt * TN);
            // publish this (batch, s-chunk) half: fence own stores, sync, add.
            __threadfence();
            __syncthreads();
            if (t == 0)
                __hip_atomic_fetch_add(&flags[bb * 16 + st], 1,
                                       __ATOMIC_RELEASE, __HIP_MEMORY_SCOPE_AGENT);
        }
        return;
    }
    rnn_body(Whw, out, hsh, bid - NWORK, t, flags + (bid - NWORK) * 16);
}

// ---------------------------------------------------------------------------
// Fallback path (no workspace): the proven two-kernel pipeline.
// ---------------------------------------------------------------------------
__global__ __launch_bounds__(256) void phase1_gemm(
    const float* __restrict__ x, const float* __restrict__ Wxw,
    const float* __restrict__ Wxb, float* __restrict__ out)
{
    __shared__ __align__(16) float As[TK][LDP];
    __shared__ __align__(16) float Bs[TK][LDP];
    gemm_tile(x, Wxw, Wxb, out, As, Bs, threadIdx.x,
              blockIdx.x * TM, blockIdx.y * TN);
}

__global__ __launch_bounds__(256, 1) void phase2_rnn(
    const float* __restrict__ Whw, float* __restrict__ out)
{
    __shared__ __align__(16) _Float16 hsh[2][4][72];
    rnn_body(Whw, out, hsh, blockIdx.x, threadIdx.x, nullptr);
}

// ---------------------------------------------------------------------------
extern "C" void kernel_launch(void* const* d_in, const int* in_sizes, int n_in,
                              void* d_out, int out_size, void* d_ws, size_t ws_size,
                              hipStream_t stream) {
    const float* x   = (const float*)d_in[0];
    const float* Wxw = (const float*)d_in[1];
    const float* Wxb = (const float*)d_in[2];
    const float* Whw = (const float*)d_in[3];
    float* out = (float*)d_out;

    if (d_ws != nullptr && ws_size >= NFLAG * sizeof(int)) {
        int* flags = (int*)d_ws;
        zero_flags<<<1, NFLAG, 0, stream>>>(flags);
        fused_srnn<<<NWORK + NRNN, 256, 0, stream>>>(x, Wxw, Wxb, Whw, out, flags);
    } else {
        dim3 g1(B * S / TM, H / TN);   // 512 x 2
        phase1_gemm<<<g1, 256, 0, stream>>>(x, Wxw, Wxb, out);
        phase2_rnn<<<B, 256, 0, stream>>>(Whw, out);
    }
}

// Round 12
// 957.965 us; speedup vs baseline: 1.1259x; 1.0026x over previous
//
#include <hip/hip_runtime.h>

#define B 32
#define S 2048
#define I 256
#define H 256

#define NWORK  64     // GEMM worker blocks (bid 0..63). Still >=2x ahead of RNN
                      // demand; half the dense-FMA power of R11 -> less throttle.
#define NRNN   32     // RNN blocks (bid 64..95), one per batch
#define NTILE  1024   // 512 M-tiles x 2 N-tiles
#define NFLAG  512    // 32 batches x 16 s-chunks
#define PFD    8      // xw prefetch depth (steps); 8*H past end stays in-bounds

typedef _Float16 h2 __attribute__((ext_vector_type(2)));
typedef float    f4 __attribute__((ext_vector_type(4)));   // native vec for NT builtins

__device__ __forceinline__ float fdot2(h2 a, h2 b, float c) {
#if __has_builtin(__builtin_amdgcn_fdot2)
    return __builtin_amdgcn_fdot2(a, b, c, false);
#else
    return fmaf((float)a[1], (float)b[1], fmaf((float)a[0], (float)b[0], c));
#endif
}

// NT store of a float4 through the native-vector builtin.
__device__ __forceinline__ void nt_store4(float* p, float4 v) {
    __builtin_nontemporal_store(__builtin_bit_cast(f4, v), (f4*)p);
}

// lgkm-only workgroup barrier. imm 0xC07F = vmcnt(63) expcnt(7) lgkmcnt(0).
__device__ __forceinline__ void lds_barrier() {
    __asm__ __volatile__("" ::: "memory");
    __builtin_amdgcn_s_waitcnt(0xC07F);
    __builtin_amdgcn_s_barrier();
    __asm__ __volatile__("" ::: "memory");
}

// tanh via exp2 with folded constant: tanh(x) = 1 - 2/(1 + 2^(x*2*log2 e)).
__device__ __forceinline__ float fast_tanh(float x) {
#if __has_builtin(__builtin_amdgcn_exp2f) && __has_builtin(__builtin_amdgcn_rcpf)
    float e = __builtin_amdgcn_exp2f(x * 2.8853900818f);   // e^(2x)
    float r = __builtin_amdgcn_rcpf(e + 1.0f);
    return fmaf(-2.0f, r, 1.0f);
#else
    float e = __expf(2.0f * x);
    return 1.0f - __fdividef(2.0f, e + 1.0f);
#endif
}

__device__ __forceinline__ float dpp_xor1(float x) {
    return __builtin_bit_cast(float, __builtin_amdgcn_mov_dpp(
        __builtin_bit_cast(int, x), 0xB1, 0xF, 0xF, false));
}
__device__ __forceinline__ float dpp_xor2(float x) {
    return __builtin_bit_cast(float, __builtin_amdgcn_mov_dpp(
        __builtin_bit_cast(int, x), 0x4E, 0xF, 0xF, false));
}

// Acquire-poll until flag reaches 2 (both N-half producers done).
// Bounded (~0.25 s at the 100 MHz constant clock; normal wait ~30 us): a
// sync bug shows as a correctness failure, never a hung container.
__device__ __forceinline__ void wait_flag(const int* f) {
    long long t0 = __builtin_amdgcn_s_memrealtime();
    while (__hip_atomic_load(f, __ATOMIC_ACQUIRE, __HIP_MEMORY_SCOPE_AGENT) != 2) {
        __builtin_amdgcn_s_sleep(8);
        if (__builtin_amdgcn_s_memrealtime() - t0 > 25000000LL) break;
    }
}

__global__ void zero_flags(int* flags) { flags[threadIdx.x] = 0; }

// ---------------------------------------------------------------------------
// GEMM tile body. xw[m][n] = sum_k x[m][k]*Wxw[n][k] + Wxb[n].
// 128x128 tile, 8x8/thread. NT xw stores: the consumer is on another XCD;
// push lines to memory clean, skip write-allocate pollution.
// ---------------------------------------------------------------------------
#define TM 128
#define TN 128
#define TK 32
#define LDP (TM + 4)

__device__ __forceinline__ void gemm_tile(
    const float* __restrict__ x, const float* __restrict__ Wxw,
    const float* __restrict__ Wxb, float* __restrict__ out,
    float (*As)[LDP], float (*Bs)[LDP], int t, int m0, int n0)
{
    const int lr = t >> 3;    // 0..31
    const int lc = t & 7;     // 0..7
    const int tn = t & 15, tm = t >> 4;

    float acc[8][8] = {};
    float bias[8];
#pragma unroll
    for (int jj = 0; jj < 4; ++jj) {
        bias[jj]     = Wxb[n0 + 4 * tn + jj];
        bias[4 + jj] = Wxb[n0 + 64 + 4 * tn + jj];
    }

    float4 va[4], vb[4];
#pragma unroll
    for (int hh = 0; hh < 4; ++hh) {             // prologue: kt=0
        const int m = lr + 32 * hh;
        va[hh] = *(const float4*)(x   + (size_t)(m0 + m) * I + 4 * lc);
        vb[hh] = *(const float4*)(Wxw + (size_t)(n0 + m) * I + 4 * lc);
    }

    for (int kt = 0; kt < I; kt += TK) {
#pragma unroll
        for (int hh = 0; hh < 4; ++hh) {         // regs -> LDS (transpose)
            const int m = lr + 32 * hh;
            float4 v = va[hh];
            As[4 * lc + 0][m] = v.x; As[4 * lc + 1][m] = v.y;
            As[4 * lc + 2][m] = v.z; As[4 * lc + 3][m] = v.w;
            float4 wv = vb[hh];
            Bs[4 * lc + 0][m] = wv.x; Bs[4 * lc + 1][m] = wv.y;
            Bs[4 * lc + 2][m] = wv.z; Bs[4 * lc + 3][m] = wv.w;
        }
        lds_barrier();
        if (kt + TK < I) {                       // prefetch kt+1
#pragma unroll
            for (int hh = 0; hh < 4; ++hh) {
                const int m = lr + 32 * hh;
                va[hh] = *(const float4*)(x   + (size_t)(m0 + m) * I + kt + TK + 4 * lc);
                vb[hh] = *(const float4*)(Wxw + (size_t)(n0 + m) * I + kt + TK + 4 * lc);
            }
        }
#pragma unroll
        for (int k = 0; k < TK; ++k) {
            float4 a0 = *(const float4*)&As[k][4 * tm];
            float4 a1 = *(const float4*)&As[k][4 * tm + 64];
            float4 b0 = *(const float4*)&Bs[k][4 * tn];
            float4 b1 = *(const float4*)&Bs[k][4 * tn + 64];
            float av[8] = {a0.x, a0.y, a0.z, a0.w, a1.x, a1.y, a1.z, a1.w};
            float bv[8] = {b0.x, b0.y, b0.z, b0.w, b1.x, b1.y, b1.z, b1.w};
#pragma unroll
            for (int i2 = 0; i2 < 8; ++i2)
#pragma unroll
                for (int jj = 0; jj < 8; ++jj)
                    acc[i2][jj] = fmaf(av[i2], bv[jj], acc[i2][jj]);
        }
        lds_barrier();
    }
#pragma unroll
    for (int hi = 0; hi < 2; ++hi) {
#pragma unroll
        for (int i2 = 0; i2 < 4; ++i2) {
            const int r = m0 + 64 * hi + 4 * tm + i2;
            float4 v0 = { acc[4 * hi + i2][0] + bias[0], acc[4 * hi + i2][1] + bias[1],
                          acc[4 * hi + i2][2] + bias[2], acc[4 * hi + i2][3] + bias[3] };
            float4 v1 = { acc[4 * hi + i2][4] + bias[4], acc[4 * hi + i2][5] + bias[5],
                          acc[4 * hi + i2][6] + bias[6], acc[4 * hi + i2][7] + bias[7] };
            nt_store4(out + (size_t)r * H + n0 + 4 * tn,      v0);
            nt_store4(out + (size_t)r * H + n0 + 64 + 4 * tn, v1);
        }
    }
}

// ---------------------------------------------------------------------------
// RNN recurrence body. Math bit-identical to R6-R11. flags==nullptr: no gate.
// R12: chunk-structured loop -- outer 16 chunks x 128 steps; the flag wait
// exists only at sl==120 (the step whose ring prefetch first crosses into
// chunk c+1), removing the per-step gate check from the hot loop.
// PFD=8 xw prefetch ring (static indices; 128 % 8 == 0 keeps p/rp static).
// ---------------------------------------------------------------------------
__device__ __forceinline__ void rnn_body(
    const float* __restrict__ Whw, float* __restrict__ out,
    _Float16 (*hsh)[4][72], int b, int t, const int* flags)
{
    const int w = t >> 6;        // wave: rows [64w, 64w+64)
    const int l = t & 63;
    const int j = l >> 2;        // quad: rows 64w+4j .. 64w+4j+3
    const int q = l & 3;         // k-quarter: k in [64q, 64q+64)

    // wreg[i][m] = W[64w+4j+(q^i)][64q + 2m .. 2m+1] as h2 (permuted rows).
    h2 wreg[4][32];
#pragma unroll
    for (int i = 0; i < 4; ++i) {
        const float4* wp =
            (const float4*)(Whw + (size_t)(64 * w + 4 * j + (q ^ i)) * H + 64 * q);
#pragma unroll
        for (int m = 0; m < 16; ++m) {
            float4 f = wp[m];
            wreg[i][2 * m]     = h2{(_Float16)f.x, (_Float16)f.y};
            wreg[i][2 * m + 1] = h2{(_Float16)f.z, (_Float16)f.w};
        }
    }
#pragma unroll
    for (int i = 0; i < 4; ++i)
#pragma unroll
        for (int m = 0; m < 32; ++m) {
            unsigned tmp = __builtin_bit_cast(unsigned, wreg[i][m]);
            __asm__("" : "+v"(tmp));
            wreg[i][m] = __builtin_bit_cast(h2, tmp);
        }

    hsh[0][w][l] = (_Float16)0.0f;
    __syncthreads();

    if (flags) {                        // gate initial xw reads on chunk 0
        if (t == 0) wait_flag(flags + 0);
        __syncthreads();
    }

    float* outb = out + (size_t)b * S * H + t;
    float* op = outb;

    // PFD-deep xw ring. Reads up to PFD steps past the end land in the
    // h_last region / its tail (in bounds for all b; values unused).
    float xr[PFD];
#pragma unroll
    for (int i = 0; i < PFD; ++i) xr[i] = outb[(size_t)i * H];
    const float* lp = outb + (size_t)PFD * H;

    float hv = 0.f;
    for (int c = 0; c < 16; ++c) {       // 16 chunks x 128 steps
#pragma unroll 8
        for (int sl = 0; sl < 128; ++sl) {
            const int p  = sl & 1;           // static (128 % 8 == 0)
            const int rp = sl & (PFD - 1);   // static ring slot
            // The sl==120 iteration's ring refill reads chunk c+1's first
            // element -- gate it. Branch exists only in the sl%8==0 slot.
            if (sl == 120 && c < 15 && flags) {
                if (t == 0) wait_flag(flags + c + 1);
                __syncthreads();
            }
            float xw0 = xr[rp];

            const uint4* hp = (const uint4*)&hsh[p][q][0];
            float acc0 = 0.f, acc1 = 0.f, acc2 = 0.f, acc3 = 0.f;
#pragma unroll
            for (int u = 0; u < 8; ++u) {
                uint4 v = hp[u];
                h2 q0 = __builtin_bit_cast(h2, v.x);
                h2 q1 = __builtin_bit_cast(h2, v.y);
                h2 q2 = __builtin_bit_cast(h2, v.z);
                h2 q3 = __builtin_bit_cast(h2, v.w);
                acc0 = fdot2(wreg[0][4 * u + 0], q0, acc0);
                acc0 = fdot2(wreg[0][4 * u + 1], q1, acc0);
                acc0 = fdot2(wreg[0][4 * u + 2], q2, acc0);
                acc0 = fdot2(wreg[0][4 * u + 3], q3, acc0);
                acc1 = fdot2(wreg[1][4 * u + 0], q0, acc1);
                acc1 = fdot2(wreg[1][4 * u + 1], q1, acc1);
                acc1 = fdot2(wreg[1][4 * u + 2], q2, acc1);
                acc1 = fdot2(wreg[1][4 * u + 3], q3, acc1);
                acc2 = fdot2(wreg[2][4 * u + 0], q0, acc2);
                acc2 = fdot2(wreg[2][4 * u + 1], q1, acc2);
                acc2 = fdot2(wreg[2][4 * u + 2], q2, acc2);
                acc2 = fdot2(wreg[2][4 * u + 3], q3, acc2);
                acc3 = fdot2(wreg[3][4 * u + 0], q0, acc3);
                acc3 = fdot2(wreg[3][4 * u + 1], q1, acc3);
                acc3 = fdot2(wreg[3][4 * u + 2], q2, acc3);
                acc3 = fdot2(wreg[3][4 * u + 3], q3, acc3);
            }

            // Select-free quad butterfly (rows pre-permuted by q^i):
            float Sa  = acc0 + dpp_xor1(acc1);
            float Sb  = acc2 + dpp_xor1(acc3);
            float sum = Sa + dpp_xor2(Sb);   // full sum for row 64w+l == t

            hv = fast_tanh(xw0 + sum);
            hsh[p ^ 1][w][l] = (_Float16)hv; // publish first (lgkm path)
            op[0] = hv;                      // outputs[b,s,t] (normal store)
            op += H;
            xr[rp] = lp[0]; lp += H;         // refill ring: step s+PFD

            lds_barrier();                   // the ONE barrier per step
        }
    }
    out[(size_t)B * S * H + (size_t)b * H + t] = hv;   // h_last
}

// ---------------------------------------------------------------------------
// Fused persistent kernel, grid = 96 blocks (<= 1 per CU; only 96 of 256 CUs
// powered to limit clock throttle during the worker window).
//   blocks 0..63  : GEMM workers (dispatched first; never wait -> no deadlock)
//   blocks 64..95 : RNN (batch = bid-64), t0 acquire-polls chunk flags
// ---------------------------------------------------------------------------
__global__ __launch_bounds__(256, 1) void fused_srnn(
    const float* __restrict__ x, const float* __restrict__ Wxw,
    const float* __restrict__ Wxb, const float* __restrict__ Whw,
    float* __restrict__ out, int* __restrict__ flags)
{
    __shared__ __align__(16) float As[TK][LDP];
    __shared__ __align__(16) float Bs[TK][LDP];
    __shared__ __align__(16) _Float16 hsh[2][4][72];

    const int bid = blockIdx.x;
    const int t   = threadIdx.x;

    if (bid < NWORK) {
        for (int tau = bid; tau < NTILE; tau += NWORK) {
            // s-major order: tau = st*64 + bb*2 + nt
            const int st = tau >> 6;
            const int bb = (tau >> 1) & 31;
            const int nt = tau & 1;
            gemm_tile(x, Wxw, Wxb, out, As, Bs, t,
                      bb * S + st * TM, nt * TN);
            // publish this (batch, s-chunk) half: fence own stores, sync, add.
            __threadfence();
            __syncthreads();
            if (t == 0)
                __hip_atomic_fetch_add(&flags[bb * 16 + st], 1,
                                       __ATOMIC_RELEASE, __HIP_MEMORY_SCOPE_AGENT);
        }
        return;
    }
    rnn_body(Whw, out, hsh, bid - NWORK, t, flags + (bid - NWORK) * 16);
}

// ---------------------------------------------------------------------------
// Fallback path (no workspace): the proven two-kernel pipeline.
// ---------------------------------------------------------------------------
__global__ __launch_bounds__(256) void phase1_gemm(
    const float* __restrict__ x, const float* __restrict__ Wxw,
    const float* __restrict__ Wxb, float* __restrict__ out)
{
    __shared__ __align__(16) float As[TK][LDP];
    __shared__ __align__(16) float Bs[TK][LDP];
    gemm_tile(x, Wxw, Wxb, out, As, Bs, threadIdx.x,
              blockIdx.x * TM, blockIdx.y * TN);
}

__global__ __launch_bounds__(256, 1) void phase2_rnn(
    const float* __restrict__ Whw, float* __restrict__ out)
{
    __shared__ __align__(16) _Float16 hsh[2][4][72];
    rnn_body(Whw, out, hsh, blockIdx.x, threadIdx.x, nullptr);
}

// ---------------------------------------------------------------------------
extern "C" void kernel_launch(void* const* d_in, const int* in_sizes, int n_in,
                              void* d_out, int out_size, void* d_ws, size_t ws_size,
                              hipStream_t stream) {
    const float* x   = (const float*)d_in[0];
    const float* Wxw = (const float*)d_in[1];
    const float* Wxb = (const float*)d_in[2];
    const float* Whw = (const float*)d_in[3];
    float* out = (float*)d_out;

    if (d_ws != nullptr && ws_size >= NFLAG * sizeof(int)) {
        int* flags = (int*)d_ws;
        zero_flags<<<1, NFLAG, 0, stream>>>(flags);
        fused_srnn<<<NWORK + NRNN, 256, 0, stream>>>(x, Wxw, Wxb, Whw, out, flags);
    } else {
        dim3 g1(B * S / TM, H / TN);   // 512 x 2
        phase1_gemm<<<g1, 256, 0, stream>>>(x, Wxw, Wxb, out);
        phase2_rnn<<<B, 256, 0, stream>>>(Whw, out);
    }
}